// Round 1
// 12421.440 us; speedup vs baseline: 2.8624x; 2.8624x over previous
//
#include <hip/hip_runtime.h>
#include <hip/hip_bf16.h>

// LSTMblock: B=64, T=1024, I=H=512, L=2.
// Persistent cooperative kernel: 256 WGs x 256 thr (1/CU).
// WG = (layer j, batch-half mb(32 rows), 8 h-cols -> 32 gate cols).
// Weights transposed into LDS once (bf16); c-state in regs.
//
// R6: fence-free coherent dataflow. The old per-step sync was a central
// 64-way ACQ_REL fetch_add + agent release/acquire fences. On gfx950 each of
// those compiles to buffer_wbl2/buffer_inv (whole-L2 writeback/invalidate)
// per WG per step -> >100 L2-wide ops per XCD per step + a 64-deep serialized
// RMW chain. Counters: MfmaUtil 0.6%, VALUBusy 1.2% -> 97%+ of each 34.7us
// step was this handshake; the L2 invalidates also forced 1.85GB of HBM
// refetch (unique input is 128MB).
// New scheme, no fences / no RMW anywhere in the T-loop:
//   - h stored write-through (sc0 sc1) into per-layer bf16 dbuf g_h[j][2][B][H]
//     (layer 1 no longer feeds back through f32 `out`; that store is now
//     output-only and stays cached/dirty in L2)
//   - producer: s_waitcnt vmcnt(0) + __syncthreads, then tid0 stores its OWN
//     per-WG flag (one 128B line each; no contention)
//   - consumer: each wave polls all 64 flags in parallel (lane i -> flag i,
//     sc0 sc1 loads), then batched sc0 sc1 h-loads + one vmcnt(0) +
//     sched_barrier(0) before the MFMA loop (rule #18)
//   - L1/L2 are never invalidated -> X slices and staging stay L2-resident.
// Flags are zeroed by detect_dtypes each launch (stream-ordered), t=0 skips
// the wait, so graph replay is safe and stale g_h is never read.
// Numerics unchanged: layer-1 h was already consumed as bf16(hv).
//
// (R5, kept): runtime per-tensor dtype detection - some tensors arrive f32.

#define B_ 64
#define T_ 1024
#define I_ 512
#define H_ 512
#define L_ 2

typedef __attribute__((ext_vector_type(8))) short bf16x8;
typedef __attribute__((ext_vector_type(4))) float f32x4;

__device__ unsigned g_flags[4][64][32];                    // 128B line per WG
__device__ __align__(16) unsigned short g_h[L_][2][B_][H_]; // per-layer h dbuf
__device__ int g_isf32[9];                                 // per-input dtype

__device__ __forceinline__ float sigm(float v)  { return 1.f / (1.f + __expf(-v)); }
__device__ __forceinline__ float tanh_(float v) { return 2.f / (1.f + __expf(-2.f * v)) - 1.f; }

__device__ __forceinline__ short f2bs(float x) {
    __hip_bfloat16 h = __float2bfloat16(x);
    return *(short*)&h;
}

// ---- coherent (write-through / L1+L2-bypass) access helpers ----
__device__ __forceinline__ void stc_u16(unsigned short* p, unsigned v) {
    asm volatile("global_store_short %0, %1, off sc0 sc1"
                 :: "v"(p), "v"(v) : "memory");
}
__device__ __forceinline__ void stc_u32(unsigned* p, unsigned v) {
    asm volatile("global_store_dword %0, %1, off sc0 sc1"
                 :: "v"(p), "v"(v) : "memory");
}
__device__ __forceinline__ unsigned ldc_u32(const unsigned* p) {
    unsigned r;
    asm volatile("global_load_dword %0, %1, off sc0 sc1\n\ts_waitcnt vmcnt(0)"
                 : "=v"(r) : "v"(p) : "memory");
    return r;
}
// NOTE: no waitcnt inside -- caller MUST s_waitcnt vmcnt(0) + sched_barrier(0)
// before consuming the result.
__device__ __forceinline__ bf16x8 ldc_b128(const unsigned short* p) {
    bf16x8 r;
    asm volatile("global_load_dwordx4 %0, %1, off sc0 sc1"
                 : "=v"(r) : "v"(p) : "memory");
    return r;
}

// 8 consecutive elements at element-offset eoff -> bf16x8 (cvt if f32).
__device__ __forceinline__ bf16x8 ld8(const void* base, size_t eoff, bool isf32) {
    if (!isf32)
        return *(const bf16x8*)((const unsigned short*)base + eoff);
    const float* f = (const float*)base + eoff;
    f32x4 a = *(const f32x4*)f;
    f32x4 b = *(const f32x4*)(f + 4);
    bf16x8 r;
    r[0] = f2bs(a[0]); r[1] = f2bs(a[1]); r[2] = f2bs(a[2]); r[3] = f2bs(a[3]);
    r[4] = f2bs(b[0]); r[5] = f2bs(b[1]); r[6] = f2bs(b[2]); r[7] = f2bs(b[3]);
    return r;
}

__device__ __forceinline__ float ld1(const void* base, size_t eoff, bool isf32) {
    return isf32 ? ((const float*)base)[eoff]
                 : __bfloat162float(((const __hip_bfloat16*)base)[eoff]);
}

__device__ __forceinline__ void st1(void* base, size_t eoff, float v, bool isf32) {
    if (isf32) ((float*)base)[eoff] = v;
    else       ((__hip_bfloat16*)base)[eoff] = __float2bfloat16(v);
}

__global__ __launch_bounds__(576)
void detect_dtypes(const void* t0, const void* t1, const void* t2,
                   const void* t3, const void* t4, const void* t5,
                   const void* t6, const void* t7, const void* t8,
                   int n0, int n1, int n2, int n3, int n4,
                   int n5, int n6, int n7, int n8)
{
    // Reset the per-WG flags for this launch (stream-ordered before lstm;
    // kernel-end implicit release makes these visible).
    for (int i = threadIdx.x; i < 256; i += 576)
        g_flags[i >> 6][i & 63][0] = 0u;

    const void* ts[9] = {t0, t1, t2, t3, t4, t5, t6, t7, t8};
    const int   ns[9] = {n0, n1, n2, n3, n4, n5, n6, n7, n8};
    const int wave = threadIdx.x >> 6;
    const int lane = threadIdx.x & 63;
    if (wave >= 9) return;
    const unsigned* p = (const unsigned*)ts[wave];
    int nw = ns[wave] / 2;            // words safely readable under EITHER dtype
    if (nw > 2048) nw = 2048;
    int cnt = 0;
    for (int i = lane; i < nw; i += 64) {
        unsigned e = (p[i] >> 7) & 0xFFu;   // low ushort's bf16 exponent field
        cnt += (e >= 130u) ? 1 : 0;         // |value| >= 8: impossible for real data
    }
    #pragma unroll
    for (int o = 32; o; o >>= 1) cnt += __shfl_down(cnt, o, 64);
    if (lane == 0) g_isf32[wave] = (cnt > nw / 8) ? 1 : 0;
}

__global__ __launch_bounds__(256)
void lstm_persistent(const void* __restrict__ X,
                     const void* __restrict__ Wf, const void* __restrict__ Bf,
                     const void* __restrict__ Wi, const void* __restrict__ Bi,
                     const void* __restrict__ Wc, const void* __restrict__ Bc,
                     const void* __restrict__ Wo, const void* __restrict__ Bo,
                     void* __restrict__ out)   // ys[B,T,H] | hT[L,B,H] | cT[L,B,H]
{
    __shared__ ushort Bt[32][1032];   // [gate*8+lcol][k]; +8 pad
    __shared__ float  Gbuf[32][36];   // gate preacts [m][n]

    const int wg   = blockIdx.x;
    const int j    = wg >> 7;
    const int mb   = (wg >> 6) & 1;
    const int nb   = wg & 63;
    const int tid  = threadIdx.x;
    const int lane = tid & 63;
    const int w    = tid >> 6;
    const int quad = lane >> 4;
    const int l15  = lane & 15;
    const int c0   = nb * 8;
    const int grp  = j * 2 + mb;

    const bool xf  = g_isf32[0] != 0;
    const bool wfl4[4] = {g_isf32[1] != 0, g_isf32[3] != 0,
                          g_isf32[5] != 0, g_isf32[7] != 0};
    const bool bfl4[4] = {g_isf32[2] != 0, g_isf32[4] != 0,
                          g_isf32[6] != 0, g_isf32[8] != 0};
    const bool outf = xf;   // policy: output dtype follows X's

    // ---- stage W slice into LDS, transposed + bf16-converted (one-time) ----
    const void* Ws[4] = {Wf, Wi, Wc, Wo};
    #pragma unroll
    for (int g = 0; g < 4; ++g) {
        for (int k = tid; k < 1024; k += 256) {
            bf16x8 v = ld8(Ws[g], ((size_t)(j * 1024 + k)) * 512 + c0, wfl4[g]);
            #pragma unroll
            for (int e = 0; e < 8; ++e) Bt[g * 8 + e][k] = (ushort)v[e];
        }
    }

    const int   col  = c0 + (tid & 7);
    const int   m_ew = tid >> 3;
    const void* Bs[4] = {Bf, Bi, Bc, Bo};
    float bias4[4];
    #pragma unroll
    for (int g = 0; g < 4; ++g) bias4[g] = ld1(Bs[g], j * H_ + col, bfl4[g]);
    float cst = 0.f;

    const int mtile  = w >> 1;
    const int ntile  = w & 1;
    const int rowb   = mb * 32 + mtile * 16 + l15;  // A-operand batch row
    const int lane_n = ntile * 16 + l15;            // gate col 0..31

    __syncthreads();

    for (int t = 0; t < T_; ++t) {
        f32x4 acc = {0.f, 0.f, 0.f, 0.f};

        // ---- x-part GEMM (K=512..1023): independent of h(t-1) ----
        {
            const size_t xo = ((size_t)rowb * T_ + t) * I_ + quad * 8;
            #pragma unroll
            for (int kk = 0; kk < 16; ++kk) {
                bf16x8 a = ld8(X, xo + kk * 32, xf);
                bf16x8 b = *(const bf16x8*)(&Bt[lane_n][512 + kk * 32 + quad * 8]);
                acc = __builtin_amdgcn_mfma_f32_16x16x32_bf16(a, b, acc, 0, 0, 0);
            }
        }

        if (t > 0) {
            // ---- wait for h(t-1): every wave polls all 64 flags in parallel
            const unsigned* fp = &g_flags[grp][lane][0];
            for (;;) {
                unsigned v = ldc_u32(fp);
                if (__all((int)(v >= (unsigned)t))) break;
                __builtin_amdgcn_s_sleep(1);
            }

            // ---- h-part GEMM (K=0..511), coherent batched loads ----
            bf16x8 af[16];
            const unsigned short* hp = &g_h[j][t & 1][rowb][quad * 8];
            #pragma unroll
            for (int kk = 0; kk < 16; ++kk) af[kk] = ldc_b128(hp + kk * 32);
            asm volatile("s_waitcnt vmcnt(0)" ::: "memory");
            __builtin_amdgcn_sched_barrier(0);
            #pragma unroll
            for (int kk = 0; kk < 16; ++kk) {
                bf16x8 b = *(const bf16x8*)(&Bt[lane_n][kk * 32 + quad * 8]);
                acc = __builtin_amdgcn_mfma_f32_16x16x32_bf16(af[kk], b, acc, 0, 0, 0);
            }
        }
        // t == 0: h0 == 0 -> h-GEMM contributes nothing.

        // ---- exchange C-tiles through LDS; elementwise LSTM update ----
        #pragma unroll
        for (int r = 0; r < 4; ++r)
            Gbuf[mtile * 16 + quad * 4 + r][lane_n] = acc[r];
        __syncthreads();

        float fv = sigm (Gbuf[m_ew][     (tid & 7)] + bias4[0]);
        float iv = sigm (Gbuf[m_ew][ 8 + (tid & 7)] + bias4[1]);
        float gv = tanh_(Gbuf[m_ew][16 + (tid & 7)] + bias4[2]);
        float ov = sigm (Gbuf[m_ew][24 + (tid & 7)] + bias4[3]);
        cst = fv * cst + iv * gv;
        float hv = ov * tanh_(cst);

        const int brow = mb * 32 + m_ew;

        // h feedback: write-through bf16 (both layers; bit-identical to the
        // old consume-as-bf16 path).
        stc_u16(&g_h[j][(t + 1) & 1][brow][col],
                (unsigned)(unsigned short)f2bs(hv));

        if (j == 1)  // ys output only (never read back) -> plain cached store
            st1(out, ((size_t)brow * T_ + t) * H_ + col, hv, outf);

        if (t == T_ - 1) {
            size_t base = (size_t)B_ * T_ * H_;
            st1(out, base + ((size_t)j * B_ + brow) * H_ + col, hv, outf);
            st1(out, base + (size_t)L_ * B_ * H_ + ((size_t)j * B_ + brow) * H_ + col,
                cst, outf);
        }

        // ---- drain own write-through stores, then signal own flag ----
        asm volatile("s_waitcnt vmcnt(0)" ::: "memory");
        __syncthreads();   // all waves' h-stores are at the coherence point
        if (tid == 0 && t < T_ - 1)
            stc_u32(&g_flags[grp][nb][0], (unsigned)(t + 1));
    }
}

extern "C" void kernel_launch(void* const* d_in, const int* in_sizes, int n_in,
                              void* d_out, int out_size, void* d_ws, size_t ws_size,
                              hipStream_t stream) {
    const void* X  = d_in[0];
    const void* Wf = d_in[1];  const void* Bf = d_in[2];
    const void* Wi = d_in[3];  const void* Bi = d_in[4];
    const void* Wc = d_in[5];  const void* Bc = d_in[6];
    const void* Wo = d_in[7];  const void* Bo = d_in[8];
    void* out = d_out;

    detect_dtypes<<<dim3(1), dim3(576), 0, stream>>>(
        X, Wf, Bf, Wi, Bi, Wc, Bc, Wo, Bo,
        in_sizes[0], in_sizes[1], in_sizes[2], in_sizes[3], in_sizes[4],
        in_sizes[5], in_sizes[6], in_sizes[7], in_sizes[8]);

    void* args[] = {&X, &Wf, &Bf, &Wi, &Bi, &Wc, &Bc, &Wo, &Bo, &out};
    hipError_t e = hipLaunchCooperativeKernel((const void*)lstm_persistent,
                                              dim3(256), dim3(256), args, 0, stream);
    if (e != hipSuccess) {
        // 256 WGs / 256 CUs at 1 WG/CU are co-resident on MI355X regardless.
        lstm_persistent<<<dim3(256), dim3(256), 0, stream>>>(
            X, Wf, Bf, Wi, Bi, Wc, Bc, Wo, Bo, out);
    }
}